// Round 4
// baseline (272.676 us; speedup 1.0000x reference)
//
#include <hip/hip_runtime.h>

#define NP 65536
#define NT 48
#define TH 0.35f
#define PPT 4   // priors per thread in kC

// ---- ws layout (bytes) ----
// 0     : float accf[4]  {loss_l, loss_landm, ce_pos, neg_sum}
// 16    : int   acci[2]  {total_pos, total_poslands}
// 24    : int   npos[16]
// 128   : u64   packed[16*48]   (per-truth best prior, packed argmax)
// 8192  : uint  hist1[16*2048]
// 139264: float lrank[16*65536] (4 MB)
#define WS_HIST1 8192
#define WS_LRANK 139264
#define WS_ZERO  139264

__device__ __forceinline__ float sml1(float d) {
    float a = fabsf(d);
    return a < 1.f ? 0.5f * a * a : a - 0.5f;
}

// ---------------- Kernel A: per-truth argmax over priors ----------------
// grid (16 prior-chunks, 6 truth-groups, 16 rows), block 256
__global__ __launch_bounds__(256) void kA(const float* __restrict__ priors,
                                          const float* __restrict__ targets,
                                          unsigned long long* __restrict__ packed) {
    const int chunk = blockIdx.x, tg = blockIdx.y, b = blockIdx.z;
    const float* tb = targets + ((size_t)b * NT + tg * 8) * 15;
    float tx1[8], ty1[8], tx2[8], ty2[8], ta[8];
#pragma unroll
    for (int j = 0; j < 8; j++) {
        tx1[j] = tb[j * 15 + 0]; ty1[j] = tb[j * 15 + 1];
        tx2[j] = tb[j * 15 + 2]; ty2[j] = tb[j * 15 + 3];
        ta[j] = (tx2[j] - tx1[j]) * (ty2[j] - ty1[j]);
    }
    const int pbase = chunk * 4096;
    float bi[8], bu[8]; unsigned int bp_[8];
#pragma unroll
    for (int j = 0; j < 8; j++) { bi[j] = 0.f; bu[j] = 1.f; bp_[j] = pbase + threadIdx.x; }
    for (int i = threadIdx.x; i < 4096; i += 256) {
        const int p = pbase + i;
        const float4 q = reinterpret_cast<const float4*>(priors)[p];
        const float px1 = q.x - q.z * 0.5f, py1 = q.y - q.w * 0.5f;
        const float px2 = q.x + q.z * 0.5f, py2 = q.y + q.w * 0.5f;
        const float areaB = (px2 - px1) * (py2 - py1);
#pragma unroll
        for (int j = 0; j < 8; j++) {
            float w = fminf(tx2[j], px2) - fmaxf(tx1[j], px1);
            float h = fminf(ty2[j], py2) - fmaxf(ty1[j], py1);
            w = fmaxf(w, 0.f); h = fmaxf(h, 0.f);
            float inter = w * h;
            float u = ta[j] + areaB - inter;
            if (inter * bu[j] > bi[j] * u) { bi[j] = inter; bu[j] = u; bp_[j] = (unsigned int)p; }
        }
    }
#pragma unroll
    for (int j = 0; j < 8; j++) {
        float iou = bi[j] / bu[j];
        unsigned long long key =
            ((unsigned long long)__float_as_uint(iou) << 32) | (unsigned long long)(~bp_[j]);
        for (int s = 32; s > 0; s >>= 1) {
            unsigned long long o = __shfl_down(key, s, 64);
            if (o > key) key = o;
        }
        if ((threadIdx.x & 63) == 0)
            atomicMax(&packed[b * NT + tg * 8 + j], key);
    }
}

// ---------------- Kernel C: per-prior match, encode, losses, lrank + fused hist1 ----------------
// grid (64, 16), block 256; each thread owns 4 consecutive priors
__global__ __launch_bounds__(256) void kC(
    const float* __restrict__ loc_data, const float* __restrict__ conf_data,
    const float* __restrict__ landm_data, const float* __restrict__ priors,
    const float* __restrict__ targets, const unsigned long long* __restrict__ packed,
    float* __restrict__ lrank, unsigned int* __restrict__ hist1,
    float* __restrict__ accf, int* __restrict__ acci, int* __restrict__ npos) {
    const int b = blockIdx.y;
    const int p0 = (blockIdx.x * 256 + threadIdx.x) * PPT;
    const int blockBase = blockIdx.x * 256 * PPT;

    __shared__ float4 tbox[NT];
    __shared__ float tlab[NT];
    __shared__ float tlm[NT][10];
    __shared__ unsigned int hist[2048];
    __shared__ int ccnt;
    __shared__ int clp[NT], clt[NT];

    // phase 0: zero hist + stage truths
    if (threadIdx.x == 0) ccnt = 0;
    for (int i = threadIdx.x; i < 2048; i += 256) hist[i] = 0;
    for (int i = threadIdx.x; i < NT * 15; i += 256) {
        int t = i / 15, f = i - t * 15;
        float v = targets[((size_t)b * NT + t) * 15 + f];
        if (f < 4) reinterpret_cast<float*>(&tbox[t])[f] = v;
        else if (f < 14) tlm[t][f - 4] = v;
        else tlab[t] = v;
    }
    __syncthreads();
    // phase 1: compact claim list for this block's prior range
    if (threadIdx.x < NT) {
        int cp = (int)(~(unsigned int)(packed[b * NT + threadIdx.x] & 0xFFFFFFFFull));
        if ((unsigned int)(cp - blockBase) < (unsigned int)(256 * PPT)) {
            int idx = atomicAdd(&ccnt, 1);
            clp[idx] = cp; clt[idx] = threadIdx.x;
        }
    }
    __syncthreads();

    // per-prior setup (4 consecutive priors, coalesced float4 loads)
    float px1[PPT], py1[PPT], px2[PPT], py2[PPT], aB[PPT];
    float bi[PPT], bu[PPT]; int bt[PPT];
#pragma unroll
    for (int j = 0; j < PPT; j++) {
        float4 q = reinterpret_cast<const float4*>(priors)[p0 + j];
        px1[j] = q.x - q.z * 0.5f; py1[j] = q.y - q.w * 0.5f;
        px2[j] = q.x + q.z * 0.5f; py2[j] = q.y + q.w * 0.5f;
        aB[j] = (px2[j] - px1[j]) * (py2[j] - py1[j]);
        bi[j] = 0.f; bu[j] = 1.f; bt[j] = 0;
    }

    // main truth loop: 1 ds_read_b128 per truth feeds 4 IoU updates
    for (int t = 0; t < NT; t++) {
        float4 tb = tbox[t];
        float ta = (tb.z - tb.x) * (tb.w - tb.y);
#pragma unroll
        for (int j = 0; j < PPT; j++) {
            float w = fminf(tb.z, px2[j]) - fmaxf(tb.x, px1[j]);
            float h = fminf(tb.w, py2[j]) - fmaxf(tb.y, py1[j]);
            w = fmaxf(w, 0.f); h = fmaxf(h, 0.f);
            float inter = w * h;
            float u = ta + aB[j] - inter;
            if (inter * bu[j] > bi[j] * u) { bi[j] = inter; bu[j] = u; bt[j] = t; }
        }
    }
    float bov[PPT];
    bool clf[PPT];
#pragma unroll
    for (int j = 0; j < PPT; j++) { bov[j] = bi[j] / bu[j]; clf[j] = false; }

    // apply claims (rare; list usually 0-1 entries). Later t wins on same prior.
    for (int i = 0; i < ccnt; i++) {
        int cp = clp[i], ct = clt[i];
        unsigned int d = (unsigned int)(cp - p0);
        if (d < PPT) {
#pragma unroll
            for (int j = 0; j < PPT; j++) {
                if (d == (unsigned int)j) {
                    bt[j] = clf[j] ? max(bt[j], ct) : ct;
                    bov[j] = 2.f; clf[j] = true;
                }
            }
        }
    }

    // epilogue: conf loads for 4 consecutive priors = 2 float4 loads
    const float4* cb4 = reinterpret_cast<const float4*>(conf_data + ((size_t)b * NP + p0) * 2);
    float4 ca = cb4[0], cbv = cb4[1];
    float cx[PPT] = {ca.x, ca.z, cbv.x, cbv.z};
    float cy[PPT] = {ca.y, ca.w, cbv.y, cbv.w};

    float sl = 0.f, slm = 0.f, cep = 0.f;
    int cp_ = 0, cpl_ = 0;
    float lr[PPT];
#pragma unroll
    for (int j = 0; j < PPT; j++) {
        const int btj = bt[j];
        const int confi = (bov[j] < TH) ? 0 : (int)tlab[btj];
        const bool pos = (confi != 0);
        const bool posl = (confi > 0);
        float m = fmaxf(cx[j], cy[j]);
        float lse = m + __logf(__expf(cx[j] - m) + __expf(cy[j] - m));
        float ce = lse - (pos ? cy[j] : cx[j]);
        lr[j] = pos ? 0.f : ce;
        atomicAdd(&hist[__float_as_uint(lr[j]) >> 20], 1u);
        if (pos) {
            cep += ce; cp_++;
            float4 q = reinterpret_cast<const float4*>(priors)[p0 + j];
            float4 tb = tbox[btj];
            float izi = 1.f / (0.1f * q.z), iwi = 1.f / (0.1f * q.w);
            float gcx = ((tb.x + tb.z) * 0.5f - q.x) * izi;
            float gcy = ((tb.y + tb.w) * 0.5f - q.y) * iwi;
            float gw = __logf((tb.z - tb.x) / q.z) * 5.f;
            float gh = __logf((tb.w - tb.y) / q.w) * 5.f;
            float4 ld = reinterpret_cast<const float4*>(loc_data)[(size_t)b * NP + p0 + j];
            sl += sml1(ld.x - gcx) + sml1(ld.y - gcy) + sml1(ld.z - gw) + sml1(ld.w - gh);
            if (posl) {
                cpl_++;
                const float* lmd = landm_data + ((size_t)b * NP + p0 + j) * 10;
#pragma unroll
                for (int i = 0; i < 5; i++) {
                    float gx = (tlm[btj][2 * i] - q.x) * izi;
                    float gy = (tlm[btj][2 * i + 1] - q.y) * iwi;
                    slm += sml1(lmd[2 * i] - gx) + sml1(lmd[2 * i + 1] - gy);
                }
            }
        }
    }
    // coalesced lrank store (4 consecutive floats)
    *reinterpret_cast<float4*>(&lrank[(size_t)b * NP + p0]) = make_float4(lr[0], lr[1], lr[2], lr[3]);

    // block reduction (4 waves)
    for (int s = 32; s > 0; s >>= 1) {
        sl += __shfl_down(sl, s, 64);
        slm += __shfl_down(slm, s, 64);
        cep += __shfl_down(cep, s, 64);
        cp_ += __shfl_down(cp_, s, 64);
        cpl_ += __shfl_down(cpl_, s, 64);
    }
    __shared__ float rf[12];
    __shared__ int ri[8];
    const int lane = threadIdx.x & 63, w = threadIdx.x >> 6;
    if (lane == 0) { rf[w] = sl; rf[4 + w] = slm; rf[8 + w] = cep; ri[w] = cp_; ri[4 + w] = cpl_; }
    __syncthreads();  // also covers LDS histogram completion
    if (threadIdx.x == 0) {
        float a = 0, bb = 0, c = 0; int d = 0, e = 0;
        for (int i = 0; i < 4; i++) { a += rf[i]; bb += rf[4 + i]; c += rf[8 + i]; d += ri[i]; e += ri[4 + i]; }
        atomicAdd(&accf[0], a);
        atomicAdd(&accf[1], bb);
        atomicAdd(&accf[2], c);
        if (d) { atomicAdd(&acci[0], d); atomicAdd(&npos[b], d); }
        if (e) atomicAdd(&acci[1], e);
    }
    // merge level-1 histogram (skip empty bins)
    for (int i = threadIdx.x; i < 2048; i += 256) {
        unsigned int c = hist[i];
        if (c) atomicAdd(&hist1[b * 2048 + i], c);
    }
}

// ---------------- Kernel F: fused top-k select + selective sum (one block per row) ----------------
__global__ __launch_bounds__(1024) void kF(const float* __restrict__ lrank,
                                           const unsigned int* __restrict__ hist1,
                                           const int* __restrict__ npos,
                                           float* __restrict__ accf) {
    const int b = blockIdx.x;
    int k = 7 * npos[b]; if (k > NP - 1) k = NP - 1;
    if (k <= 0) return;  // uniform for whole block

    __shared__ unsigned int h2[2048];
    __shared__ unsigned int part[256];
    __shared__ int sbin1, sbin2;
    __shared__ unsigned int sacc1, sacc2;
    __shared__ float wsum[16];

    const unsigned int* gh = hist1 + b * 2048;
    if (threadIdx.x < 256) {
        unsigned int s = 0;
#pragma unroll
        for (int i = 0; i < 8; i++) s += gh[threadIdx.x * 8 + i];
        part[threadIdx.x] = s;
    }
    for (int i = threadIdx.x; i < 2048; i += 1024) h2[i] = 0;
    __syncthreads();
    if (threadIdx.x == 0) {
        unsigned int kk = (unsigned int)k, acc = 0; int g = 255;
        for (; g > 0; --g) { unsigned int pg = part[g]; if (acc + pg >= kk) break; acc += pg; }
        int bin = g * 8;
        for (int i = 7; i >= 0; --i) {
            unsigned int c = gh[g * 8 + i];
            if (acc + c >= kk) { bin = g * 8 + i; break; }
            acc += c;
        }
        sbin1 = bin; sacc1 = acc;
    }
    __syncthreads();
    const unsigned int b1 = (unsigned int)sbin1;
    const float4* v4 = reinterpret_cast<const float4*>(lrank + (size_t)b * NP);
    for (int i = threadIdx.x; i < NP / 4; i += 1024) {
        float4 x = v4[i];
        unsigned int u0 = __float_as_uint(x.x), u1 = __float_as_uint(x.y);
        unsigned int u2 = __float_as_uint(x.z), u3 = __float_as_uint(x.w);
        if ((u0 >> 20) == b1) atomicAdd(&h2[(u0 >> 9) & 2047], 1u);
        if ((u1 >> 20) == b1) atomicAdd(&h2[(u1 >> 9) & 2047], 1u);
        if ((u2 >> 20) == b1) atomicAdd(&h2[(u2 >> 9) & 2047], 1u);
        if ((u3 >> 20) == b1) atomicAdd(&h2[(u3 >> 9) & 2047], 1u);
    }
    __syncthreads();
    if (threadIdx.x < 256) {
        unsigned int s = 0;
#pragma unroll
        for (int i = 0; i < 8; i++) s += h2[threadIdx.x * 8 + i];
        part[threadIdx.x] = s;
    }
    __syncthreads();
    if (threadIdx.x == 0) {
        unsigned int k1 = (unsigned int)k - sacc1, acc = 0; int g = 255;
        for (; g > 0; --g) { unsigned int pg = part[g]; if (acc + pg >= k1) break; acc += pg; }
        int bin = g * 8;
        for (int i = 7; i >= 0; --i) {
            unsigned int c = h2[g * 8 + i];
            if (acc + c >= k1) { bin = g * 8 + i; break; }
            acc += c;
        }
        sbin2 = bin; sacc2 = acc;
    }
    __syncthreads();
    const unsigned int k2 = (unsigned int)k - sacc1 - sacc2;
    const unsigned int pfx = (b1 << 11) | (unsigned int)sbin2;  // bits 30..9
    float sum = 0.f;
    for (int i = threadIdx.x; i < NP / 4; i += 1024) {
        float4 x = v4[i];
        if ((__float_as_uint(x.x) >> 9) > pfx) sum += x.x;
        if ((__float_as_uint(x.y) >> 9) > pfx) sum += x.y;
        if ((__float_as_uint(x.z) >> 9) > pfx) sum += x.z;
        if ((__float_as_uint(x.w) >> 9) > pfx) sum += x.w;
    }
    for (int s = 32; s > 0; s >>= 1) sum += __shfl_down(sum, s, 64);
    const int lane = threadIdx.x & 63, w = threadIdx.x >> 6;
    if (lane == 0) wsum[w] = sum;
    __syncthreads();
    if (threadIdx.x == 0) {
        float tot = 0.f;
        for (int i = 0; i < 16; i++) tot += wsum[i];
        tot += (float)k2 * __uint_as_float((pfx << 9) | 256u);  // boundary-bin ties at bin midpoint
        atomicAdd(&accf[3], tot);
    }
}

// ---------------- Kernel E: finalize ----------------
__global__ void kE(const float* __restrict__ accf, const int* __restrict__ acci,
                   float* __restrict__ out) {
    if (threadIdx.x == 0) {
        float N = fmaxf((float)acci[0], 1.f);
        float N1 = fmaxf((float)acci[1], 1.f);
        out[0] = accf[0] / N;
        out[1] = (accf[2] + accf[3]) / N;
        out[2] = accf[1] / N1;
    }
}

extern "C" void kernel_launch(void* const* d_in, const int* in_sizes, int n_in,
                              void* d_out, int out_size, void* d_ws, size_t ws_size,
                              hipStream_t stream) {
    const float* loc_data = (const float*)d_in[0];
    const float* conf_data = (const float*)d_in[1];
    const float* landm_data = (const float*)d_in[2];
    const float* priors = (const float*)d_in[3];
    const float* targets = (const float*)d_in[4];
    float* out = (float*)d_out;
    char* ws = (char*)d_ws;
    float* accf = (float*)ws;
    int* acci = (int*)(ws + 16);
    int* npos = (int*)(ws + 24);
    unsigned long long* packed = (unsigned long long*)(ws + 128);
    unsigned int* hist1 = (unsigned int*)(ws + WS_HIST1);
    float* lrank = (float*)(ws + WS_LRANK);

    hipMemsetAsync(d_ws, 0, WS_ZERO, stream);
    kA<<<dim3(16, 6, 16), 256, 0, stream>>>(priors, targets, packed);
    kC<<<dim3(64, 16), 256, 0, stream>>>(loc_data, conf_data, landm_data, priors, targets,
                                         packed, lrank, hist1, accf, acci, npos);
    kF<<<16, 1024, 0, stream>>>(lrank, hist1, npos, accf);
    kE<<<1, 64, 0, stream>>>(accf, acci, out);
}